// Round 3
// baseline (86.038 us; speedup 1.0000x reference)
//
#include <hip/hip_runtime.h>

// Exact closed form via Heisenberg propagation.
//
// Circuit: RX(x_j+w0_j) per qubit -> CNOT ring -> RX(w1_j) -> CNOT ring -> <Z_q>.
// Bit c = 9 - qubit j. Ring index map m: m_c = k_c^k_{c+1} (c=0..7),
// m8 = k8^k9^k0, m9 = k9^k0  (columns of m == R2 kernel's verified pair masks).
// <Z_q> = <prod| Ring^dag [prod_{c in S_q} (g_c Z_c + s_c Y_c)] Ring |prod>,
// S_q = row_{9-q}(m^-1):
//   q=0:0x1FF q=1:0x300 q=2:0x380 q=3:0x3C0 q=4:0x3E0
//   q=5:0x3F0 q=6:0x3F8 q=7:0x3FC q=8:0x3FE q=9:0x3FF
// (rows cross-checked: m^-2 rows reproduce R2's verified 0x355 / 0x2AA.)
// Each branch (Y on T, Z on S\T) conjugates through 10 CNOTs via a 16-entry
// Pauli table (CNOT conj is Pauli -> +/-Pauli, real signs only). X factor => 0.
// Survivors: coef = sign * prod(T: sin w1) * prod(S\T: cos w1); value =
// coef * prod(zmask: cos a_c) * prod(ymask: -sin a_c),  a_c = x_{9-c}+w0_{9-c}.
//
// CNOT conj table, encoding I=0,X=1,Y=2,Z=3, idx=(Pc<<2)|Pt, nibble=(Pc'<<2)|Pt':
//   (I,Y)->(Z,Y) (I,Z)->(Z,Z) (X,I)->(X,X) (X,Y)->(Y,Z) (X,Z)->-(Y,Y)
//   (Y,I)->(Y,X) (Y,X)->(Y,I) (Y,Y)->-(X,Z) (Y,Z)->(X,Y) (Z,Y)->(I,Y) (Z,Z)->(I,Z)
#define NQ 10

__global__ void precompute_terms(const float* __restrict__ weights,
                                 int* __restrict__ cnt,       // [16] ints
                                 float2* __restrict__ terms)  // [10*1024]
{
    __shared__ int scnt[NQ];
    const int tid = threadIdx.x;
    if (tid < NQ) scnt[tid] = 0;
    __syncthreads();

    // layer-2 angles per bit c: theta_c = w1[9-c] = weights[10 + 9 - c]
    float g[NQ], sg[NQ];
    #pragma unroll
    for (int c = 0; c < NQ; ++c) {
        const float th = weights[NQ + 9 - c];
        __sincosf(th, &sg[c], &g[c]);
    }

    const unsigned long long LUT = 0x32DC6789AB45FE10ull;
    const unsigned SIGNM = 0x0480u;   // minus at idx 7 (X,Z) and 10 (Y,Y)
    const int S[NQ] = {0x1FF,0x300,0x380,0x3C0,0x3E0,0x3F0,0x3F8,0x3FC,0x3FE,0x3FF};

    for (int q = 0; q < NQ; ++q) {
        const int s    = S[q];
        const int nsub = 1 << __popc(s);
        for (int i = tid; i < nsub; i += (int)blockDim.x) {
            unsigned code = 0;           // 2 bits per bit-position
            float coef = 1.f;
            int rem = i;
            #pragma unroll
            for (int c = 0; c < NQ; ++c) {
                if ((s >> c) & 1) {
                    if (rem & 1) { code |= 2u << (2*c); coef *= sg[c]; }
                    else         { code |= 3u << (2*c); coef *= g[c]; }
                    rem >>= 1;
                }
            }
            // conjugate through ring: step st: control bit st, target (st+9)%10
            unsigned sign = 0;
            #pragma unroll
            for (int st = 0; st < NQ; ++st) {
                const int cc = st, tt = (st + 9) % NQ;
                const unsigned p_c = (code >> (2*cc)) & 3u;
                const unsigned p_t = (code >> (2*tt)) & 3u;
                const unsigned idx = (p_c << 2) | p_t;
                const unsigned nib = (unsigned)((LUT >> (4*idx)) & 0xFull);
                code &= ~((3u << (2*cc)) | (3u << (2*tt)));
                code |= (nib >> 2)  << (2*cc);
                code |= (nib & 3u)  << (2*tt);
                sign ^= (SIGNM >> idx) & 1u;
            }
            int zmask = 0, ymask = 0; bool dead = false;
            #pragma unroll
            for (int c = 0; c < NQ; ++c) {
                const unsigned p = (code >> (2*c)) & 3u;
                if (p == 1u) dead = true;
                else if (p == 3u) zmask |= 1 << c;
                else if (p == 2u) ymask |= 1 << c;
            }
            if (dead) continue;
            if (sign) coef = -coef;
            const int slot = atomicAdd(&scnt[q], 1);
            terms[q*1024 + slot] =
                make_float2(coef, __uint_as_float((unsigned)zmask | ((unsigned)ymask << 16)));
        }
    }
    __syncthreads();
    if (tid < NQ) cnt[tid] = scnt[tid];
}

__global__ __launch_bounds__(256)
void eval_kernel(const float* __restrict__ inputs,
                 const float* __restrict__ weights,
                 const int* __restrict__ cnt,
                 const float2* __restrict__ terms,
                 float* __restrict__ out, int B)
{
    const int wave = (blockIdx.x * blockDim.x + threadIdx.x) >> 6;
    const int lane = threadIdx.x & 63;
    if (wave >= B) return;

    // a_c = x[9-c] + w0[9-c]; <Z>=cos a, <Y>=-sin a on RX(a)|0>
    float cz[NQ], sy[NQ];
    const float* xe = inputs + wave * NQ;
    #pragma unroll
    for (int c = 0; c < NQ; ++c) {
        const float a = xe[9 - c] + weights[9 - c];
        float sn, cs; __sincosf(a, &sn, &cs);
        cz[c] = cs; sy[c] = -sn;
    }

    float res[NQ];
    #pragma unroll
    for (int q = 0; q < NQ; ++q) {
        const int n = cnt[q];
        float ssum = 0.f;
        for (int t = lane; t < n; t += 64) {
            const float2 rec = terms[q*1024 + t];
            const unsigned mk = __float_as_uint(rec.y);
            const unsigned zm = mk & 0xFFFFu, ym = mk >> 16;
            float p = rec.x;
            #pragma unroll
            for (int c = 0; c < NQ; ++c) {
                float f = ((zm >> c) & 1) ? cz[c] : 1.f;
                f       = ((ym >> c) & 1) ? sy[c] : f;
                p *= f;
            }
            ssum += p;
        }
        res[q] = ssum;
    }

    // butterfly reduce each res[q] across the wave
    #pragma unroll
    for (int off = 32; off >= 1; off >>= 1) {
        #pragma unroll
        for (int q = 0; q < NQ; ++q)
            res[q] += __shfl_xor(res[q], off, 64);
    }

    float v = 0.f;
    #pragma unroll
    for (int q = 0; q < NQ; ++q)
        if (lane == q) v = res[q];
    if (lane < NQ) out[wave * NQ + lane] = v;
}

extern "C" void kernel_launch(void* const* d_in, const int* in_sizes, int n_in,
                              void* d_out, int out_size, void* d_ws, size_t ws_size,
                              hipStream_t stream) {
    const float* inputs  = (const float*)d_in[0];
    const float* weights = (const float*)d_in[1];
    float* out = (float*)d_out;
    const int B = in_sizes[0] / NQ;            // 8192

    int*    cnt   = (int*)d_ws;                // 64 B
    float2* terms = (float2*)((char*)d_ws + 64);  // 80 KB

    precompute_terms<<<1, 256, 0, stream>>>(weights, cnt, terms);
    eval_kernel<<<(B + 3) / 4, 256, 0, stream>>>(inputs, weights, cnt, terms, out, B);
}

// Round 5
// 67.614 us; speedup vs baseline: 1.2725x; 1.2725x over previous
//
#include <hip/hip_runtime.h>

// Exact closed form via Heisenberg propagation, term enumeration at COMPILE
// TIME (constexpr). Propagation logic is a verbatim port of the R3 runtime
// version validated on hardware (absmax 2.4e-4): same LUT, sign mask,
// subset->sin assignment (LSB-first over set bits of S by increasing c), and
// CNOT step order (st=0..9, ctrl=st, tgt=(st+9)%10).
//
// <Z_q> = sum over surviving branches of
//   sign * prod_{c in S_q, tmask} sin(w1[9-c]) * prod_{c in S_q, !tmask} cos(w1[9-c])
//        * prod_{zm} cos(a_c) * prod_{ym} (-sin(a_c)),   a_c = x[9-c] + w0[9-c].

#define NQ 10

struct QTerms { unsigned t[1024]; int n; };

constexpr unsigned long long kLUT = 0x32DC6789AB45FE10ull;
constexpr unsigned kSIGN = 0x0480u;   // minus at idx 7 (X,Z) and 10 (Y,Y)
constexpr int kS[NQ] = {0x1FF,0x300,0x380,0x3C0,0x3E0,0x3F0,0x3F8,0x3FC,0x3FE,0x3FF};

constexpr QTerms gen(int q) {
    QTerms r{};
    const int s = kS[q];
    int pc = 0;
    for (int c = 0; c < NQ; ++c) pc += (s >> c) & 1;
    const int nsub = 1 << pc;
    for (int i = 0; i < nsub; ++i) {
        unsigned code = 0, tmask = 0;
        int rem = i;
        for (int c = 0; c < NQ; ++c) {
            if ((s >> c) & 1) {
                if (rem & 1) { code |= 2u << (2*c); tmask |= 1u << c; }
                else         { code |= 3u << (2*c); }
                rem >>= 1;
            }
        }
        unsigned sign = 0;
        for (int st = 0; st < NQ; ++st) {
            const int cc = st, tt = (st + 9) % NQ;
            const unsigned p_c = (code >> (2*cc)) & 3u;
            const unsigned p_t = (code >> (2*tt)) & 3u;
            const unsigned idx = (p_c << 2) | p_t;
            const unsigned nib = (unsigned)((kLUT >> (4*idx)) & 0xFull);
            code &= ~((3u << (2*cc)) | (3u << (2*tt)));
            code |= (nib >> 2) << (2*cc);
            code |= (nib & 3u) << (2*tt);
            sign ^= (kSIGN >> idx) & 1u;
        }
        unsigned zm = 0, ym = 0; bool dead = false;
        for (int c = 0; c < NQ; ++c) {
            const unsigned p = (code >> (2*c)) & 3u;
            if (p == 1u) dead = true;          // <X> = 0 kills the branch
            else if (p == 3u) zm |= 1u << c;
            else if (p == 2u) ym |= 1u << c;
        }
        if (dead) continue;
        r.t[r.n++] = tmask | (zm << 10) | (ym << 20) | (sign << 30);
    }
    return r;
}

// one constexpr evaluation per variable: stays within clang's constexpr budget
constexpr QTerms cT0 = gen(0); constexpr QTerms cT1 = gen(1);
constexpr QTerms cT2 = gen(2); constexpr QTerms cT3 = gen(3);
constexpr QTerms cT4 = gen(4); constexpr QTerms cT5 = gen(5);
constexpr QTerms cT6 = gen(6); constexpr QTerms cT7 = gen(7);
constexpr QTerms cT8 = gen(8); constexpr QTerms cT9 = gen(9);

__device__ const QTerms dT0 = cT0; __device__ const QTerms dT1 = cT1;
__device__ const QTerms dT2 = cT2; __device__ const QTerms dT3 = cT3;
__device__ const QTerms dT4 = cT4; __device__ const QTerms dT5 = cT5;
__device__ const QTerms dT6 = cT6; __device__ const QTerms dT7 = cT7;
__device__ const QTerms dT8 = cT8; __device__ const QTerms dT9 = cT9;

constexpr int kN[NQ] = {cT0.n, cT1.n, cT2.n, cT3.n, cT4.n,
                        cT5.n, cT6.n, cT7.n, cT8.n, cT9.n};

// cross-lane xor move: DPP for 1,2,8 (VALU pipe); ds_swizzle 4,16; bpermute 32
template<int LMASK>
__device__ __forceinline__ float lxor(float x, int a32) {
    if constexpr (LMASK == 1)
        return __int_as_float(__builtin_amdgcn_update_dpp(
            __float_as_int(x), __float_as_int(x), 0xB1, 0xF, 0xF, true));
    else if constexpr (LMASK == 2)
        return __int_as_float(__builtin_amdgcn_update_dpp(
            __float_as_int(x), __float_as_int(x), 0x4E, 0xF, 0xF, true));
    else if constexpr (LMASK == 8)
        return __int_as_float(__builtin_amdgcn_update_dpp(
            __float_as_int(x), __float_as_int(x), 0x128, 0xF, 0xF, true));
    else if constexpr (LMASK == 32)
        return __int_as_float(__builtin_amdgcn_ds_bpermute(a32, __float_as_int(x)));
    else
        return __int_as_float(__builtin_amdgcn_ds_swizzle(
            __float_as_int(x), (LMASK << 10) | 0x1F));
}

template<int Q>
__device__ __forceinline__ float eval_q(const unsigned* __restrict__ tq,
                                        const float (&g)[NQ], const float (&sg)[NQ],
                                        const float (&cz)[NQ], const float (&sy)[NQ],
                                        int lane) {
    constexpr int S = kS[Q];
    constexpr int N = kN[Q];
    float ssum = 0.f;
    for (int t = lane; t < N; t += 64) {
        const unsigned w = tq[t];
        float p = 1.f;
        #pragma unroll
        for (int c = 0; c < NQ; ++c) {
            // (S >> c) & 1 folds to a constant per unrolled iteration
            if ((S >> c) & 1)
                p *= ((w >> c) & 1u) ? sg[c] : g[c];
            const unsigned zb = (w >> (10 + c)) & 1u;
            const unsigned yb = (w >> (20 + c)) & 1u;
            float f = zb ? cz[c] : 1.f;
            f = yb ? sy[c] : f;
            p *= f;
        }
        ssum += (w & (1u << 30)) ? -p : p;
    }
    return ssum;
}

__global__ __launch_bounds__(256)
void eval_kernel(const float* __restrict__ inputs,
                 const float* __restrict__ weights,
                 float* __restrict__ out, int B)
{
    const int wave = (blockIdx.x * blockDim.x + threadIdx.x) >> 6;
    const int lane = threadIdx.x & 63;
    if (wave >= B) return;
    const int a32 = (lane ^ 32) << 2;

    float g[NQ], sg[NQ], cz[NQ], sy[NQ];
    const float* xe = inputs + wave * NQ;
    #pragma unroll
    for (int c = 0; c < NQ; ++c) {
        const float th = weights[NQ + 9 - c];      // w1 (full angle)
        __sincosf(th, &sg[c], &g[c]);
        const float a = xe[9 - c] + weights[9 - c]; // x + w0
        float sn, cs; __sincosf(a, &sn, &cs);
        cz[c] = cs; sy[c] = -sn;
    }

    float res[NQ];
    res[0] = eval_q<0>(dT0.t, g, sg, cz, sy, lane);
    res[1] = eval_q<1>(dT1.t, g, sg, cz, sy, lane);
    res[2] = eval_q<2>(dT2.t, g, sg, cz, sy, lane);
    res[3] = eval_q<3>(dT3.t, g, sg, cz, sy, lane);
    res[4] = eval_q<4>(dT4.t, g, sg, cz, sy, lane);
    res[5] = eval_q<5>(dT5.t, g, sg, cz, sy, lane);
    res[6] = eval_q<6>(dT6.t, g, sg, cz, sy, lane);
    res[7] = eval_q<7>(dT7.t, g, sg, cz, sy, lane);
    res[8] = eval_q<8>(dT8.t, g, sg, cz, sy, lane);
    res[9] = eval_q<9>(dT9.t, g, sg, cz, sy, lane);

    // butterfly reduce: DPP stages (1,2,8) on VALU, ds only for 4,16,32
    #pragma unroll
    for (int q = 0; q < NQ; ++q) res[q] += lxor< 1>(res[q], a32);
    #pragma unroll
    for (int q = 0; q < NQ; ++q) res[q] += lxor< 2>(res[q], a32);
    #pragma unroll
    for (int q = 0; q < NQ; ++q) res[q] += lxor< 8>(res[q], a32);
    #pragma unroll
    for (int q = 0; q < NQ; ++q) res[q] += lxor< 4>(res[q], a32);
    #pragma unroll
    for (int q = 0; q < NQ; ++q) res[q] += lxor<16>(res[q], a32);
    #pragma unroll
    for (int q = 0; q < NQ; ++q) res[q] += lxor<32>(res[q], a32);

    float v = 0.f;
    #pragma unroll
    for (int q = 0; q < NQ; ++q)
        if (lane == q) v = res[q];
    if (lane < NQ) out[wave * NQ + lane] = v;
}

extern "C" void kernel_launch(void* const* d_in, const int* in_sizes, int n_in,
                              void* d_out, int out_size, void* d_ws, size_t ws_size,
                              hipStream_t stream) {
    const float* inputs  = (const float*)d_in[0];
    const float* weights = (const float*)d_in[1];
    float* out = (float*)d_out;
    const int B = in_sizes[0] / NQ;     // 8192
    eval_kernel<<<(B + 3) / 4, 256, 0, stream>>>(inputs, weights, out, B);
}

// Round 6
// 65.052 us; speedup vs baseline: 1.3226x; 1.0394x over previous
//
#include <hip/hip_runtime.h>

// Exact closed form via Heisenberg propagation (compile-time term tables,
// HW-validated in R5: absmax 2.4e-4). R6 split:
//  - coef_kernel (batch-independent): C_k = sign * prod sin/cos(w1) per term,
//    fully parallel, compile-time counts, no atomics. Writes float2(C, masks).
//  - eval_kernel: per element, per term: p = C * prod_zm cos(a_c) * prod_ym(-sin a_c),
//    a_c = x[9-c] + w0[9-c]. c-loop guarded by compile-time per-q support union.

#define NQ 10

struct QTerms { unsigned t[1024]; int n; };

constexpr unsigned long long kLUT = 0x32DC6789AB45FE10ull;
constexpr unsigned kSIGN = 0x0480u;   // minus at idx 7 (X,Z) and 10 (Y,Y)
constexpr int kS[NQ] = {0x1FF,0x300,0x380,0x3C0,0x3E0,0x3F0,0x3F8,0x3FC,0x3FE,0x3FF};

constexpr QTerms gen(int q) {
    QTerms r{};
    const int s = kS[q];
    int pc = 0;
    for (int c = 0; c < NQ; ++c) pc += (s >> c) & 1;
    const int nsub = 1 << pc;
    for (int i = 0; i < nsub; ++i) {
        unsigned code = 0, tmask = 0;
        int rem = i;
        for (int c = 0; c < NQ; ++c) {
            if ((s >> c) & 1) {
                if (rem & 1) { code |= 2u << (2*c); tmask |= 1u << c; }
                else         { code |= 3u << (2*c); }
                rem >>= 1;
            }
        }
        unsigned sign = 0;
        for (int st = 0; st < NQ; ++st) {
            const int cc = st, tt = (st + 9) % NQ;
            const unsigned p_c = (code >> (2*cc)) & 3u;
            const unsigned p_t = (code >> (2*tt)) & 3u;
            const unsigned idx = (p_c << 2) | p_t;
            const unsigned nib = (unsigned)((kLUT >> (4*idx)) & 0xFull);
            code &= ~((3u << (2*cc)) | (3u << (2*tt)));
            code |= (nib >> 2) << (2*cc);
            code |= (nib & 3u) << (2*tt);
            sign ^= (kSIGN >> idx) & 1u;
        }
        unsigned zm = 0, ym = 0; bool dead = false;
        for (int c = 0; c < NQ; ++c) {
            const unsigned p = (code >> (2*c)) & 3u;
            if (p == 1u) dead = true;          // <X> = 0 kills the branch
            else if (p == 3u) zm |= 1u << c;
            else if (p == 2u) ym |= 1u << c;
        }
        if (dead) continue;
        r.t[r.n++] = tmask | (zm << 10) | (ym << 20) | (sign << 30);
    }
    return r;
}

constexpr QTerms cT0 = gen(0); constexpr QTerms cT1 = gen(1);
constexpr QTerms cT2 = gen(2); constexpr QTerms cT3 = gen(3);
constexpr QTerms cT4 = gen(4); constexpr QTerms cT5 = gen(5);
constexpr QTerms cT6 = gen(6); constexpr QTerms cT7 = gen(7);
constexpr QTerms cT8 = gen(8); constexpr QTerms cT9 = gen(9);

constexpr int kN[NQ] = {cT0.n, cT1.n, cT2.n, cT3.n, cT4.n,
                        cT5.n, cT6.n, cT7.n, cT8.n, cT9.n};

// ---- flatten terms + cos-masks (S \ tmask) with per-q offsets ----
struct Flat { unsigned w[4096]; unsigned cm[4096]; int off[11]; };

constexpr void appendF(Flat& f, const QTerms& T, int S, int q, int& k) {
    f.off[q] = k;
    for (int j = 0; j < T.n; ++j) {
        const unsigned w = T.t[j];
        f.w[k]  = w;
        f.cm[k] = (unsigned)S & ~(w & 0x3FFu);   // cos sites of the w1 product
        ++k;
    }
}

constexpr Flat buildFlat() {
    Flat f{};
    int k = 0;
    appendF(f, cT0, kS[0], 0, k); appendF(f, cT1, kS[1], 1, k);
    appendF(f, cT2, kS[2], 2, k); appendF(f, cT3, kS[3], 3, k);
    appendF(f, cT4, kS[4], 4, k); appendF(f, cT5, kS[5], 5, k);
    appendF(f, cT6, kS[6], 6, k); appendF(f, cT7, kS[7], 7, k);
    appendF(f, cT8, kS[8], 8, k); appendF(f, cT9, kS[9], 9, k);
    f.off[10] = k;
    return f;
}

constexpr Flat cF = buildFlat();
constexpr int kTOT = cF.off[10];
constexpr int kOff[NQ] = {cF.off[0],cF.off[1],cF.off[2],cF.off[3],cF.off[4],
                          cF.off[5],cF.off[6],cF.off[7],cF.off[8],cF.off[9]};

// per-q union of zm|ym over SURVIVING terms (compile-time loop guard)
constexpr unsigned calcU(int q) {
    unsigned u = 0;
    for (int j = cF.off[q]; j < cF.off[q+1]; ++j) {
        const unsigned w = cF.w[j];
        u |= ((w >> 10) & 0x3FFu) | ((w >> 20) & 0x3FFu);
    }
    return u;
}
constexpr unsigned kU[NQ] = {calcU(0),calcU(1),calcU(2),calcU(3),calcU(4),
                             calcU(5),calcU(6),calcU(7),calcU(8),calcU(9)};

__device__ const Flat dF = cF;

// ---- batch-independent coefficient kernel: C_k from weights row 1 ----
__global__ __launch_bounds__(256)
void coef_kernel(const float* __restrict__ weights, float2* __restrict__ coefs) {
    const int i = blockIdx.x * blockDim.x + threadIdx.x;
    if (i >= kTOT) return;
    const unsigned w  = dF.w[i];
    const unsigned cm = dF.cm[i];
    float C = (w & (1u << 30)) ? -1.f : 1.f;
    #pragma unroll
    for (int c = 0; c < NQ; ++c) {
        float sn, cs;
        __sincosf(weights[NQ + 9 - c], &sn, &cs);   // w1 full angle
        if ((w >> c) & 1u)       C *= sn;
        else if ((cm >> c) & 1u) C *= cs;
    }
    coefs[i] = make_float2(C, __uint_as_float(w));
}

// cross-lane xor move: DPP for 1,2,8 (VALU pipe); ds_swizzle 4,16; bpermute 32
template<int LMASK>
__device__ __forceinline__ float lxor(float x, int a32) {
    if constexpr (LMASK == 1)
        return __int_as_float(__builtin_amdgcn_update_dpp(
            __float_as_int(x), __float_as_int(x), 0xB1, 0xF, 0xF, true));
    else if constexpr (LMASK == 2)
        return __int_as_float(__builtin_amdgcn_update_dpp(
            __float_as_int(x), __float_as_int(x), 0x4E, 0xF, 0xF, true));
    else if constexpr (LMASK == 8)
        return __int_as_float(__builtin_amdgcn_update_dpp(
            __float_as_int(x), __float_as_int(x), 0x128, 0xF, 0xF, true));
    else if constexpr (LMASK == 32)
        return __int_as_float(__builtin_amdgcn_ds_bpermute(a32, __float_as_int(x)));
    else
        return __int_as_float(__builtin_amdgcn_ds_swizzle(
            __float_as_int(x), (LMASK << 10) | 0x1F));
}

template<int Q>
__device__ __forceinline__ float eval_q(const float2* __restrict__ coefs,
                                        const float (&cz)[NQ], const float (&sy)[NQ],
                                        int lane) {
    constexpr int N = kN[Q];
    constexpr int OFF = kOff[Q];
    constexpr unsigned U = kU[Q];
    float ssum = 0.f;
    for (int t = lane; t < N; t += 64) {
        const float2 r = coefs[OFF + t];
        const unsigned w = __float_as_uint(r.y);
        float p = r.x;
        #pragma unroll
        for (int c = 0; c < NQ; ++c) {
            if ((U >> c) & 1u) {               // folds per unrolled iteration
                const unsigned zb = (w >> (10 + c)) & 1u;
                const unsigned yb = (w >> (20 + c)) & 1u;
                float f = zb ? cz[c] : 1.f;
                f = yb ? sy[c] : f;
                p *= f;
            }
        }
        ssum += p;
    }
    return ssum;
}

__global__ __launch_bounds__(256)
void eval_kernel(const float* __restrict__ inputs,
                 const float* __restrict__ weights,
                 const float2* __restrict__ coefs,
                 float* __restrict__ out, int B)
{
    const int wave = (blockIdx.x * blockDim.x + threadIdx.x) >> 6;
    const int lane = threadIdx.x & 63;
    if (wave >= B) return;
    const int a32 = (lane ^ 32) << 2;

    float cz[NQ], sy[NQ];
    const float* xe = inputs + wave * NQ;
    #pragma unroll
    for (int c = 0; c < NQ; ++c) {
        const float a = xe[9 - c] + weights[9 - c];  // x + w0
        float sn, cs; __sincosf(a, &sn, &cs);
        cz[c] = cs; sy[c] = -sn;
    }

    float res[NQ];
    res[0] = eval_q<0>(coefs, cz, sy, lane);
    res[1] = eval_q<1>(coefs, cz, sy, lane);
    res[2] = eval_q<2>(coefs, cz, sy, lane);
    res[3] = eval_q<3>(coefs, cz, sy, lane);
    res[4] = eval_q<4>(coefs, cz, sy, lane);
    res[5] = eval_q<5>(coefs, cz, sy, lane);
    res[6] = eval_q<6>(coefs, cz, sy, lane);
    res[7] = eval_q<7>(coefs, cz, sy, lane);
    res[8] = eval_q<8>(coefs, cz, sy, lane);
    res[9] = eval_q<9>(coefs, cz, sy, lane);

    // butterfly reduce: DPP stages (1,2,8) on VALU, ds only for 4,16,32
    #pragma unroll
    for (int q = 0; q < NQ; ++q) res[q] += lxor< 1>(res[q], a32);
    #pragma unroll
    for (int q = 0; q < NQ; ++q) res[q] += lxor< 2>(res[q], a32);
    #pragma unroll
    for (int q = 0; q < NQ; ++q) res[q] += lxor< 8>(res[q], a32);
    #pragma unroll
    for (int q = 0; q < NQ; ++q) res[q] += lxor< 4>(res[q], a32);
    #pragma unroll
    for (int q = 0; q < NQ; ++q) res[q] += lxor<16>(res[q], a32);
    #pragma unroll
    for (int q = 0; q < NQ; ++q) res[q] += lxor<32>(res[q], a32);

    float v = 0.f;
    #pragma unroll
    for (int q = 0; q < NQ; ++q)
        if (lane == q) v = res[q];
    if (lane < NQ) out[wave * NQ + lane] = v;
}

extern "C" void kernel_launch(void* const* d_in, const int* in_sizes, int n_in,
                              void* d_out, int out_size, void* d_ws, size_t ws_size,
                              hipStream_t stream) {
    const float* inputs  = (const float*)d_in[0];
    const float* weights = (const float*)d_in[1];
    float* out = (float*)d_out;
    const int B = in_sizes[0] / NQ;            // 8192

    float2* coefs = (float2*)d_ws;             // kTOT * 8 bytes (< 32 KB)

    coef_kernel<<<(kTOT + 255) / 256, 256, 0, stream>>>(weights, coefs);
    eval_kernel<<<(B + 3) / 4, 256, 0, stream>>>(inputs, weights, coefs, out, B);
}

// Round 7
// 54.482 us; speedup vs baseline: 1.5792x; 1.1940x over previous
//
#include <hip/hip_runtime.h>

// Exact closed form via a 4-state Pauli transfer-matrix contraction.
//
// Circuit: RX(x_j + w0_j) -> CNOT ring -> RX(w1_j) -> CNOT ring -> <Z_q>.
// Site c = 9 - qubit j. alpha_c = x[9-c]+w0[9-c]; beta_c = w1[9-c].
// Per site: cz=cos(alpha), sy=-sin(alpha) (product-state <Z>,<Y>), g=cos(beta),
// s=sin(beta) (Heisenberg RX split Z -> gZ + sY).
//
// The branch sum over 2^|S_q| Pauli strings (HW-validated in R3/R5, absmax
// 2.4e-4) collapses exactly: CNOT step st touches (ctrl=st, tgt=st-1), so
// branches form a Markov chain over the carry Pauli u in {I,X,Y,Z}.
// Active-site transfer T_k (columns, from the validated LUT):
//   T e_I = g_k e_Z ; T e_X = s_k e_Y ;
//   T e_Y = g_k*sy_{k-1} e_I - s_k*cz_{k-1} e_X ;
//   T e_Z = g_k*cz_{k-1} e_I + s_k*sy_{k-1} e_X
// Inactive site: e_Z -> cz_{k-1} e_Z (prefix scalar).
// Step-9 boundary rows over u8 (m9 = site-9 mid Pauli):
//   B_Z.w = cz9*wI + sy8*wY + cz8*wZ ; B_Y.w = sy9*wX ;
//   B_I.w = wI + cz9*sy8*wY + cz9*cz8*wZ ; B_X.w = sy9*cz8*wY - sy9*sy8*wZ
// Step-0 branches: q=1..8 (site0 inactive): u0=Z, m9=Z w/ g9 | Y w/ s9.
//   q=9: (Z,Z)->u0=I,m9=Z,g0g9 ; (Z,Y)->I,Y,g0s9 ; (Y,Z)->X,Y,s0g9 ; (Y,Y)->X,Z,-s0s9.
//   q=0: (Z,I)->u0=Z,m9=I,g0 ; (Y,I)->u0=Y,m9=X,s0.
// Cross-checks: w1=0 reproduces HW-verified double-ring sign rows
// 0x2FF (q=1), 0x2AA (q=9), 0x355 (q=0); q=1 full branch trace matches.
//
// One THREAD per batch element (~500 VALU ops); 8192 threads total.

#define NQ 10

__global__ __launch_bounds__(64)
void qeval_kernel(const float* __restrict__ inputs,
                  const float* __restrict__ weights,
                  float* __restrict__ out, int B)
{
    const int b = blockIdx.x * 64 + threadIdx.x;
    if (b >= B) return;

    float cz[NQ], sy[NQ], g[NQ], s[NQ];
    #pragma unroll
    for (int c = 0; c < NQ; ++c) {
        const float a = inputs[b * NQ + 9 - c] + weights[9 - c];   // x + w0
        float sn, cs; __sincosf(a, &sn, &cs);
        cz[c] = cs; sy[c] = -sn;
        float sb, cb; __sincosf(weights[NQ + 9 - c], &sb, &cb);    // w1
        g[c] = cb; s[c] = sb;
    }

    // inactive-prefix products: pref[k] = cz0*...*cz[k-2], pref[1] = 1
    float pref[9];
    pref[1] = 1.f;
    #pragma unroll
    for (int k = 2; k <= 8; ++k) pref[k] = pref[k - 1] * cz[k - 2];

    // suffix columns C_u(k) = (T_8 ... T_k) e_u ; k=9 -> identity
    float CI[4] = {1.f, 0.f, 0.f, 0.f};
    float CX[4] = {0.f, 1.f, 0.f, 0.f};
    float CY[4] = {0.f, 0.f, 1.f, 0.f};
    float CZ[4] = {0.f, 0.f, 0.f, 1.f};

    float res[NQ];

    #pragma unroll
    for (int k = 8; k >= 1; --k) {
        const float a  = g[k] * sy[k - 1];
        const float bb = s[k] * cz[k - 1];
        const float d  = g[k] * cz[k - 1];
        const float e  = s[k] * sy[k - 1];
        float nI[4], nX[4], nY[4], nZ[4];
        #pragma unroll
        for (int j = 0; j < 4; ++j) {
            nI[j] = g[k] * CZ[j];
            nX[j] = s[k] * CY[j];
            nY[j] = a * CI[j] - bb * CX[j];
            nZ[j] = d * CI[j] + e * CX[j];
        }
        #pragma unroll
        for (int j = 0; j < 4; ++j) {
            CI[j] = nI[j]; CX[j] = nX[j]; CY[j] = nY[j]; CZ[j] = nZ[j];
        }
        // q = 9-k in 1..8: v = Z-column of G_k, scaled by inactive prefix
        res[9 - k] = pref[k] * ( g[9] * (cz[9]*CZ[0] + sy[8]*CZ[2] + cz[8]*CZ[3])
                               + s[9] * sy[9] * CZ[1] );
    }

    // q = 9 (sites 0 and 9 both active at step 0)
    {
        const float BZ_CI = cz[9]*CI[0] + sy[8]*CI[2] + cz[8]*CI[3];
        const float BY_CI = sy[9]*CI[1];
        const float BZ_CX = cz[9]*CX[0] + sy[8]*CX[2] + cz[8]*CX[3];
        const float BY_CX = sy[9]*CX[1];
        res[9] = g[0]*g[9]*BZ_CI + g[0]*s[9]*BY_CI
               + s[0]*g[9]*BY_CX - s[0]*s[9]*BZ_CX;
    }
    // q = 0 (site 9 inactive: m9 in {I, X})
    {
        const float BI_CZ = CZ[0] + cz[9]*sy[8]*CZ[2] + cz[9]*cz[8]*CZ[3];
        const float BX_CY = sy[9]*cz[8]*CY[2] - sy[9]*sy[8]*CY[3];
        res[0] = g[0]*BI_CZ + s[0]*BX_CY;
    }

    #pragma unroll
    for (int q = 0; q < NQ; ++q) out[b * NQ + q] = res[q];
}

extern "C" void kernel_launch(void* const* d_in, const int* in_sizes, int n_in,
                              void* d_out, int out_size, void* d_ws, size_t ws_size,
                              hipStream_t stream) {
    const float* inputs  = (const float*)d_in[0];
    const float* weights = (const float*)d_in[1];
    float* out = (float*)d_out;
    const int B = in_sizes[0] / NQ;            // 8192
    qeval_kernel<<<(B + 63) / 64, 64, 0, stream>>>(inputs, weights, out, B);
}